// Round 1
// baseline (171.851 us; speedup 1.0000x reference)
//
#include <hip/hip_runtime.h>
#include <hip/hip_bf16.h>
#include <math.h>

#define D_EMB 512
#define HD 64
#define BB 8
#define NN 2048
#define MROWS (BB*NN)   // 16384

typedef short short8  __attribute__((ext_vector_type(8)));
typedef short short4v __attribute__((ext_vector_type(4)));
typedef float f32x4   __attribute__((ext_vector_type(4)));

// scale(1/sqrt(512)) * log2(e): folded into Qb so P = exp2(S') directly
#define QSCALE 0.063758708f

__device__ __forceinline__ short f2bf(float x){
    unsigned u = __float_as_uint(x);
    unsigned r = (u + 0x7fffu + ((u >> 16) & 1u)) >> 16;
    return (short)r;
}
__device__ __forceinline__ float bf2f(short b){
    return __uint_as_float(((unsigned)(unsigned short)b) << 16);
}
__device__ __forceinline__ unsigned pkbf(float a, float b){
    __hip_bfloat162 h = __float22bfloat162_rn(make_float2(a, b));
    unsigned u; __builtin_memcpy(&u, &h, 4); return u;
}
// async global->LDS, 16B per lane (global_load_lds_dwordx4)
__device__ __forceinline__ void gl16(const short* g, short* l){
    __builtin_amdgcn_global_load_lds(
        (const __attribute__((address_space(1))) unsigned*)g,
        (__attribute__((address_space(3))) unsigned*)l, 16, 0, 0);
}

// ---------------- Wtf: W[k][n] f32 -> bf16 in MFMA B-frag order
// off = ((c16*4 + t)*64 + lane)*8 + j  with c16=k>>5, t=n>>4,
// lane=((k>>3)&3)*16 + (n&15), j=k&7
// 64 blocks (was 8): the 8-block version kept only 8 CUs busy and ran
// latency-bound on the scattered f32 gathers.
__global__ __launch_bounds__(256)
void wt_kernel(const float* __restrict__ W, short* __restrict__ Wtf){
    for (int idx = blockIdx.x * 256 + threadIdx.x; idx < D_EMB*HD; idx += 64*256){
        int k = idx >> 6, n = idx & 63;
        int off = (((k >> 5)*4 + (n >> 4))*64 + ((k >> 3) & 3)*16 + (n & 15))*8 + (k & 7);
        Wtf[off] = f2bf(W[idx]);
    }
}

// ---------------- Projection. 16 rows/wave, MFMA, 4-deep X prefetch.
// R9: Wtf staged to LDS once per block. Rationale: vmcnt is IN-ORDER, so
// per-iteration Wtf global loads (L1-hit) forced every MFMA to drain the
// older in-flight X HBM prefetches -> effective prefetch depth ~1 ->
// 1.39 TB/s / 41 us (counters: MfmaUtil 2.6, VALUBusy 4, occ 25 = pure
// latency). With B-frags on lgkmcnt (ds_read) the vmcnt queue is X-only;
// the 4-deep prefetch holds vmcnt(6) across the loop. 64 KB LDS -> 2
// blocks/CU = 8 waves/CU, each with ~6 KB in flight >> the ~9 KB/CU
// needed to saturate HBM at ~900 cy latency.
__global__ __launch_bounds__(256, 2)
void proj_kernel(const float* __restrict__ Xq, const float* __restrict__ Xk,
                 const float* __restrict__ Xv, const short* __restrict__ Wtf,
                 short* __restrict__ Qb, short* __restrict__ Kb,
                 short* __restrict__ Vt)
{
    __shared__ short sW[D_EMB*HD];          // 64 KiB, frag order
    const int tid = threadIdx.x;
    const int lane = tid & 63;
    const int lc = lane & 15, quad = lane >> 4;
    const int wid = blockIdx.x * 4 + (tid >> 6);
    const int m0 = wid * 16;
    const int tensor = m0 >> 14;             // 0=Q 1=K 2=V
    const int rloc = m0 & (MROWS - 1);
    const float* X = (tensor == 0) ? Xq : (tensor == 1 ? Xk : Xv);
    const float* xbase = X + (size_t)(rloc + lc)*D_EMB + quad*8;

    // Issue the X prefetch first so its HBM latency overlaps the Wtf stage;
    // the staging __syncthreads drains vmcnt(0) once, then the loop's
    // queue contains only X loads.
    float4 xa[4][2];
#pragma unroll
    for (int p = 0; p < 4; ++p){
        xa[p][0] = *(const float4*)(xbase + p*32);
        xa[p][1] = *(const float4*)(xbase + p*32 + 4);
    }

    // Stage Wtf -> LDS: 16 passes x 256 threads x 16 B = 64 KiB.
    // Dest is wave-uniform base + lane*16B as global_load_lds requires.
#pragma unroll
    for (int pass = 0; pass < 16; ++pass)
        gl16(Wtf + pass*2048 + tid*8, sW + pass*2048 + tid*8);

    f32x4 acc[4];
#pragma unroll
    for (int t = 0; t < 4; ++t)
#pragma unroll
        for (int r = 0; r < 4; ++r) acc[t][r] = 0.f;

    __syncthreads();

#pragma unroll
    for (int c16 = 0; c16 < 16; ++c16){
        float4 f0 = xa[c16 & 3][0], f1 = xa[c16 & 3][1];
        if (c16 < 12){
            xa[c16 & 3][0] = *(const float4*)(xbase + (c16+4)*32);
            xa[c16 & 3][1] = *(const float4*)(xbase + (c16+4)*32 + 4);
        }
        union { short8 s8; unsigned u[4]; } a;
        a.u[0] = pkbf(f0.x, f0.y); a.u[1] = pkbf(f0.z, f0.w);
        a.u[2] = pkbf(f1.x, f1.y); a.u[3] = pkbf(f1.z, f1.w);
#pragma unroll
        for (int t = 0; t < 4; ++t){
            short8 bf = *(const short8*)&sW[((c16*4 + t)*64 + lane)*8];
            acc[t] = __builtin_amdgcn_mfma_f32_16x16x32_bf16(a.s8, bf, acc[t], 0,0,0);
        }
    }

    if (tensor == 0){
#pragma unroll
        for (int t = 0; t < 4; ++t)
#pragma unroll
            for (int r = 0; r < 4; ++r)
                Qb[(size_t)(rloc + quad*4 + r)*HD + t*16 + lc] = f2bf(acc[t][r] * QSCALE);
    } else if (tensor == 1){
        // K tile: tile=R>>6; off = nin*64 + ((d>>3)^(nin&7))*8 + (d&7)
#pragma unroll
        for (int t = 0; t < 4; ++t)
#pragma unroll
            for (int r = 0; r < 4; ++r){
                const int R = rloc + quad*4 + r;
                const int nin = R & 63;
                const int off = ((R >> 6) << 12) + nin*64
                              + ((((t << 1) | (lc >> 3)) ^ (nin & 7)) << 3) + (lc & 7);
                Kb[off] = f2bf(acc[t][r]);
            }
    } else {
        // V tile: tile=R>>6; off = d*64 + ((nin>>3)^(d&7))*8 + (nin&7)
#pragma unroll
        for (int t = 0; t < 4; ++t)
#pragma unroll
            for (int r = 0; r < 4; ++r){
                const int R = rloc + quad*4 + r;
                const int nin = R & 63;
                const int d = t*16 + lc;
                const int off = ((R >> 6) << 12) + d*64
                              + (((nin >> 3) ^ (lc & 7)) << 3) + (nin & 7);
                Vt[off] = f2bf(acc[t][r]);
            }
    }
}

// ---------------- Attention: block = (b, 64-row q-block j, k-chunk c).
// 4 waves share double-buffered global_load_lds-staged K/V tiles. (unchanged)
template<int SH>
__global__ __launch_bounds__(256)
void attn_part(const short* __restrict__ Qb, const short* __restrict__ Kb,
               const short* __restrict__ Vt, const unsigned char* __restrict__ pad,
               const int* __restrict__ mflag, float* __restrict__ out,
               float* __restrict__ Lp, short* __restrict__ Op)
{
    constexpr int M   = 1 << SH;
    constexpr int NG  = 32 / M;
    constexpr int UPB = M * NG * (NG + 1) / 2;
    constexpr int PPB = UPB - M;

    __shared__ short sK[2][4096];
    __shared__ short sV[2][4096];
    __shared__ short sP[4][16][80];

    const int tid = threadIdx.x, lane = tid & 63, lc = lane & 15, quad = lane >> 4, w = tid >> 6;
    const int unit = blockIdx.x;
    const int b = unit / UPB;
    const int rem = unit - b * UPB;
    int a = 0;
    while (rem >= (M * (a + 1) * (a + 2)) / 2) ++a;
    const int u = rem - M * a * (a + 1) / 2;
    const int C = a + 1;
    const int r = u / C, c = u - r * C;
    const int j = a * M + r;
    const int q0 = j * 64;

    const bool causal = (mflag[0] != 0);
    const int T = causal ? (j + 1) : 32;
    const int qq = (T + C - 1) / C;
    const int t0 = c * qq;
    const int t1 = min(t0 + qq, T);
    const int tb = b * 32;
    const unsigned char* padb = pad + (size_t)b * NN;

    const short* qrow = Qb + ((size_t)b * NN + q0 + w*16 + lc) * HD;
    const short8 qf0 = *(const short8*)(qrow + quad * 8);
    const short8 qf1 = *(const short8*)(qrow + 32 + quad * 8);

    f32x4 o[4];
#pragma unroll
    for (int t = 0; t < 4; ++t)
#pragma unroll
        for (int rr = 0; rr < 4; ++rr) o[t][rr] = 0.f;
    float lacc = 0.f;

    {
        const short* gk = Kb + ((size_t)(tb + t0) << 12) + w*1024 + lane*8;
        const short* gv = Vt + ((size_t)(tb + t0) << 12) + w*1024 + lane*8;
        short* lk = &sK[0][w*1024 + lane*8];
        short* lv = &sV[0][w*1024 + lane*8];
        gl16(gk, lk); gl16(gk + 512, lk + 512);
        gl16(gv, lv); gl16(gv + 512, lv + 512);
    }

    int buf = 0;
    const int sw = lc & 7;
    for (int kt = t0; kt < t1; ++kt, buf ^= 1){
        __syncthreads();
        if (kt + 1 < t1){
            const short* gk = Kb + ((size_t)(tb + kt + 1) << 12) + w*1024 + lane*8;
            const short* gv = Vt + ((size_t)(tb + kt + 1) << 12) + w*1024 + lane*8;
            short* lk = &sK[buf ^ 1][w*1024 + lane*8];
            short* lv = &sV[buf ^ 1][w*1024 + lane*8];
            gl16(gk, lk); gl16(gk + 512, lk + 512);
            gl16(gv, lv); gl16(gv + 512, lv + 512);
        }
        const int k0 = kt * 64;
        short8 kf0[4], kf1[4], vf0[4], vf1[4];
#pragma unroll
        for (int t = 0; t < 4; ++t){
            const int row = (t*16 + lc) * 64;
            kf0[t] = *(const short8*)&sK[buf][row + ((quad ^ sw) << 3)];
            kf1[t] = *(const short8*)&sK[buf][row + (((quad + 4) ^ sw) << 3)];
            vf0[t] = *(const short8*)&sV[buf][row + ((quad ^ sw) << 3)];
            vf1[t] = *(const short8*)&sV[buf][row + (((quad + 4) ^ sw) << 3)];
        }
        f32x4 st[4];
#pragma unroll
        for (int t = 0; t < 4; ++t){
#pragma unroll
            for (int rr = 0; rr < 4; ++rr) st[t][rr] = 0.f;
            st[t] = __builtin_amdgcn_mfma_f32_16x16x32_bf16(kf0[t], qf0, st[t], 0,0,0);
            st[t] = __builtin_amdgcn_mfma_f32_16x16x32_bf16(kf1[t], qf1, st[t], 0,0,0);
        }
        const bool dg = causal && (kt == j);
        const int thr = q0 + w*16 + lc - k0;
#pragma unroll
        for (int t = 0; t < 4; ++t){
            uchar4 pb = *(const uchar4*)(padb + k0 + t*16 + quad*4);
            float e[4];
#pragma unroll
            for (int rr = 0; rr < 4; ++rr){
                float v = st[t][rr];
                const unsigned char pr = (rr==0)?pb.x:(rr==1)?pb.y:(rr==2)?pb.z:pb.w;
                const int nloc = t*16 + quad*4 + rr;
                if (pr || (dg && nloc > thr)) v = -INFINITY;
                e[rr] = exp2f(v);
                lacc += e[rr];
            }
            union { short4v s4; unsigned uu[2]; } pk;
            pk.uu[0] = pkbf(e[0], e[1]);
            pk.uu[1] = pkbf(e[2], e[3]);
            *(short4v*)&sP[w][lc][t*16 + quad*4] = pk.s4;
        }
        const short8 pf0 = *(const short8*)&sP[w][lc][quad*8];
        const short8 pf1 = *(const short8*)&sP[w][lc][32 + quad*8];
#pragma unroll
        for (int t = 0; t < 4; ++t){
            o[t] = __builtin_amdgcn_mfma_f32_16x16x32_bf16(pf0, vf0[t], o[t], 0,0,0);
            o[t] = __builtin_amdgcn_mfma_f32_16x16x32_bf16(pf1, vf1[t], o[t], 0,0,0);
        }
    }

    lacc += __shfl_xor(lacc, 16);
    lacc += __shfl_xor(lacc, 32);

    if (C == 1){
        float linv[4];
#pragma unroll
        for (int rr = 0; rr < 4; ++rr) linv[rr] = 1.f / __shfl(lacc, quad*4 + rr);
#pragma unroll
        for (int rr = 0; rr < 4; ++rr){
            float* orow = out + ((size_t)b*NN + q0 + w*16 + quad*4 + rr)*HD;
#pragma unroll
            for (int t = 0; t < 4; ++t) orow[t*16 + lc] = o[t][rr] * linv[rr];
        }
    } else {
        const int pu = b*PPB + (M*a*(a+1)/2 - M) + r*C + c;
        short* op = Op + (size_t)pu * 4096;
#pragma unroll
        for (int t = 0; t < 4; ++t)
#pragma unroll
            for (int rr = 0; rr < 4; ++rr)
                op[(w*16 + quad*4 + rr)*64 + t*16 + lc] = f2bf(o[t][rr]);
        if (lane < 16) Lp[pu*64 + w*16 + lane] = lacc;
    }
}

// ---------------- Combine: one thread per output element.
template<int SH>
__global__ __launch_bounds__(256)
void attn_combine(const float* __restrict__ Lp, const short* __restrict__ Op,
                  float* __restrict__ out)
{
    constexpr int M    = 1 << SH;
    constexpr int UPB  = M * (32/M) * (32/M + 1) / 2;
    constexpr int PPB  = UPB - M;
    constexpr int NSTR = 32 - M;
    const int tid = threadIdx.x, lane = tid & 63;
    const int unit = blockIdx.x;
    const int per_b = NSTR * 16;
    const int b = unit / per_b;
    const int rem = unit - b * per_b;
    const int j = M + (rem >> 4);
    const int row = (rem & 15) * 4 + (tid >> 6);
    const int a = j >> SH;
    const int C = a + 1;
    const int r = j - a * M;
    const int pu0 = b*PPB + (M*a*(a+1)/2 - M) + r*C;

    float l = 0.f, acc = 0.f;
    for (int cc = 0; cc < C; ++cc){
        l   += Lp[(pu0 + cc)*64 + row];
        acc += bf2f(Op[(size_t)(pu0 + cc)*4096 + row*64 + lane]);
    }
    out[((size_t)b*NN + j*64 + row)*HD + lane] = acc / l;
}

extern "C" void kernel_launch(void* const* d_in, const int* in_sizes, int n_in,
                              void* d_out, int out_size, void* d_ws, size_t ws_size,
                              hipStream_t stream) {
    const float* key_in   = (const float*)d_in[0];
    const float* query_in = (const float*)d_in[1];
    const float* value_in = (const float*)d_in[2];
    const unsigned char* pad = (const unsigned char*)d_in[3];
    const int* mflag      = (const int*)d_in[4];
    const float* Wk       = (const float*)d_in[5];
    // W_query / W_value unused — reference applies W_key to Q, K and V.

    short* Qb = (short*)d_ws;                    // 2 MiB (pre-scaled by QSCALE)
    short* Kb = Qb + (size_t)MROWS*HD;           // 2 MiB, swizzled tiles
    short* Vt = Kb + (size_t)MROWS*HD;           // 2 MiB, swizzled tiles [d][n]
    short* Wtf = Vt + (size_t)MROWS*HD;          // 64 KiB, frag order
    float* Lp = (float*)(Wtf + D_EMB*HD);

    wt_kernel<<<64, 256, 0, stream>>>(Wk, Wtf);
    proj_kernel<<<768, 256, 0, stream>>>(query_in, key_in, value_in, Wtf, Qb, Kb, Vt);

    if (ws_size >= (size_t)15818752){
        // SH=2: 1152 part-blocks, <=4 tiles each; Lp 1120*64 f32, Op 1120*4096 bf16
        short* Op = (short*)(Lp + 1120*64);
        attn_part<2><<<1152, 256, 0, stream>>>(Qb, Kb, Vt, pad, mflag, (float*)d_out, Lp, Op);
        attn_combine<2><<<BB*28*16, 256, 0, stream>>>(Lp, Op, (float*)d_out);
    } else {
        // SH=3: 640 part-blocks, <=8 tiles each; 11.2 MB total (proven fit)
        short* Op = (short*)(Lp + 576*64);
        attn_part<3><<<640, 256, 0, stream>>>(Qb, Kb, Vt, pad, mflag, (float*)d_out, Lp, Op);
        attn_combine<3><<<BB*24*16, 256, 0, stream>>>(Lp, Op, (float*)d_out);
    }
}

// Round 2
// 167.987 us; speedup vs baseline: 1.0230x; 1.0230x over previous
//
#include <hip/hip_runtime.h>
#include <hip/hip_bf16.h>
#include <math.h>

#define D_EMB 512
#define HD 64
#define BB 8
#define NN 2048
#define MROWS (BB*NN)   // 16384

typedef short short8  __attribute__((ext_vector_type(8)));
typedef short short4v __attribute__((ext_vector_type(4)));
typedef float f32x4   __attribute__((ext_vector_type(4)));

// scale(1/sqrt(512)) * log2(e): folded into Qb so P = exp2(S') directly
#define QSCALE 0.063758708f

__device__ __forceinline__ short f2bf(float x){
    unsigned u = __float_as_uint(x);
    unsigned r = (u + 0x7fffu + ((u >> 16) & 1u)) >> 16;
    return (short)r;
}
__device__ __forceinline__ float bf2f(short b){
    return __uint_as_float(((unsigned)(unsigned short)b) << 16);
}
__device__ __forceinline__ unsigned pkbf(float a, float b){
    __hip_bfloat162 h = __float22bfloat162_rn(make_float2(a, b));
    unsigned u; __builtin_memcpy(&u, &h, 4); return u;
}
// async global->LDS, 16B per lane (global_load_lds_dwordx4)
__device__ __forceinline__ void gl16(const short* g, short* l){
    __builtin_amdgcn_global_load_lds(
        (const __attribute__((address_space(1))) unsigned*)g,
        (__attribute__((address_space(3))) unsigned*)l, 16, 0, 0);
}

// ---------------- Wtf: W[k][n] f32 -> bf16 in MFMA B-frag order
// off = ((c16*4 + t)*64 + lane)*8 + j  with c16=k>>5, t=n>>4,
// lane=((k>>3)&3)*16 + (n&15), j=k&7
__global__ __launch_bounds__(256)
void wt_kernel(const float* __restrict__ W, short* __restrict__ Wtf){
    for (int idx = blockIdx.x * 256 + threadIdx.x; idx < D_EMB*HD; idx += 64*256){
        int k = idx >> 6, n = idx & 63;
        int off = (((k >> 5)*4 + (n >> 4))*64 + ((k >> 3) & 3)*16 + (n & 15))*8 + (k & 7);
        Wtf[off] = f2bf(W[idx]);
    }
}

// ---------------- Projection, R10: split-K front-loaded waves.
// Post-mortem R8/R9: both landed at 1.37 TB/s. R8's VGPR_Count=32 proves
// the compiler SANK the rolling 4-deep prefetch to use sites (xa[4][2]
// alone is 32 VGPRs) -> each of 16 iterations exposed ~900cy latency.
// R9 (LDS-staged Wtf) kept regs but halved occupancy -> same product.
// Fix: each wave owns 16 rows x HALF of K (256 floats). ALL 16 float4
// loads are issued before any use (nothing to sink behind) -> 16 KB in
// flight per wave for one latency, then 8 compute iterations on
// L2-resident Wtf frags. Two waves per row-group f32-reduce via 8 KB LDS.
// Grid 1536 (6 blocks/CU); launch_bounds(256,4) caps VGPR at 128.
__global__ __launch_bounds__(256, 4)
void proj_kernel(const float* __restrict__ Xq, const float* __restrict__ Xk,
                 const float* __restrict__ Xv, const short* __restrict__ Wtf,
                 short* __restrict__ Qb, short* __restrict__ Kb,
                 short* __restrict__ Vt)
{
    __shared__ float sRed[2][64][16];       // 8 KiB: kh=1 partials
    const int tid = threadIdx.x;
    const int lane = tid & 63;
    const int lc = lane & 15, quad = lane >> 4;
    const int w = tid >> 6;
    const int pair = w >> 1;                 // 0,1: row-group within block
    const int kh = w & 1;                    // 0,1: K-half
    const int grp = blockIdx.x * 2 + pair;
    const int m0 = grp * 16;
    const int tensor = m0 >> 14;             // 0=Q 1=K 2=V
    const int rloc = m0 & (MROWS - 1);
    const float* X = (tensor == 0) ? Xq : (tensor == 1 ? Xk : Xv);
    const float* xbase = X + (size_t)(rloc + lc)*D_EMB + kh*256 + quad*8;

    // Front-load the whole K-half: 16 float4 = 64 VGPRs, all in flight.
    float4 xa[8][2];
#pragma unroll
    for (int p = 0; p < 8; ++p){
        xa[p][0] = *(const float4*)(xbase + p*32);
        xa[p][1] = *(const float4*)(xbase + p*32 + 4);
    }

    f32x4 acc[4];
#pragma unroll
    for (int t = 0; t < 4; ++t)
#pragma unroll
        for (int r = 0; r < 4; ++r) acc[t][r] = 0.f;

#pragma unroll
    for (int c = 0; c < 8; ++c){
        const int c16 = kh*8 + c;
        union { short8 s8; unsigned u[4]; } a;
        a.u[0] = pkbf(xa[c][0].x, xa[c][0].y); a.u[1] = pkbf(xa[c][0].z, xa[c][0].w);
        a.u[2] = pkbf(xa[c][1].x, xa[c][1].y); a.u[3] = pkbf(xa[c][1].z, xa[c][1].w);
#pragma unroll
        for (int t = 0; t < 4; ++t){
            short8 bf = *(const short8*)(Wtf + (size_t)(((c16*4 + t)*64 + lane)*8));
            acc[t] = __builtin_amdgcn_mfma_f32_16x16x32_bf16(a.s8, bf, acc[t], 0,0,0);
        }
    }

    // Cross-wave K reduction: kh=1 writes, kh=0 sums + epilogue.
    // Slot XOR (t ^ (lane&3)) spreads the 2-bank pattern to 8 banks.
    if (kh == 1){
#pragma unroll
        for (int t = 0; t < 4; ++t)
            *(f32x4*)&sRed[pair][lane][(t ^ (lane & 3))*4] = acc[t];
    }
    __syncthreads();
    if (kh != 0) return;

#pragma unroll
    for (int t = 0; t < 4; ++t){
        f32x4 p = *(const f32x4*)&sRed[pair][lane][(t ^ (lane & 3))*4];
#pragma unroll
        for (int r = 0; r < 4; ++r) acc[t][r] += p[r];
    }

    if (tensor == 0){
#pragma unroll
        for (int t = 0; t < 4; ++t)
#pragma unroll
            for (int r = 0; r < 4; ++r)
                Qb[(size_t)(rloc + quad*4 + r)*HD + t*16 + lc] = f2bf(acc[t][r] * QSCALE);
    } else if (tensor == 1){
        // K tile: tile=R>>6; off = nin*64 + ((d>>3)^(nin&7))*8 + (d&7)
#pragma unroll
        for (int t = 0; t < 4; ++t)
#pragma unroll
            for (int r = 0; r < 4; ++r){
                const int R = rloc + quad*4 + r;
                const int nin = R & 63;
                const int off = ((R >> 6) << 12) + nin*64
                              + ((((t << 1) | (lc >> 3)) ^ (nin & 7)) << 3) + (lc & 7);
                Kb[off] = f2bf(acc[t][r]);
            }
    } else {
        // V tile: tile=R>>6; off = d*64 + ((nin>>3)^(d&7))*8 + (nin&7)
#pragma unroll
        for (int t = 0; t < 4; ++t)
#pragma unroll
            for (int r = 0; r < 4; ++r){
                const int R = rloc + quad*4 + r;
                const int nin = R & 63;
                const int d = t*16 + lc;
                const int off = ((R >> 6) << 12) + d*64
                              + (((nin >> 3) ^ (lc & 7)) << 3) + (nin & 7);
                Vt[off] = f2bf(acc[t][r]);
            }
    }
}

// ---------------- Attention: block = (b, 64-row q-block j, k-chunk c).
// 4 waves share double-buffered global_load_lds-staged K/V tiles. (unchanged)
template<int SH>
__global__ __launch_bounds__(256)
void attn_part(const short* __restrict__ Qb, const short* __restrict__ Kb,
               const short* __restrict__ Vt, const unsigned char* __restrict__ pad,
               const int* __restrict__ mflag, float* __restrict__ out,
               float* __restrict__ Lp, short* __restrict__ Op)
{
    constexpr int M   = 1 << SH;
    constexpr int NG  = 32 / M;
    constexpr int UPB = M * NG * (NG + 1) / 2;
    constexpr int PPB = UPB - M;

    __shared__ short sK[2][4096];
    __shared__ short sV[2][4096];
    __shared__ short sP[4][16][80];

    const int tid = threadIdx.x, lane = tid & 63, lc = lane & 15, quad = lane >> 4, w = tid >> 6;
    const int unit = blockIdx.x;
    const int b = unit / UPB;
    const int rem = unit - b * UPB;
    int a = 0;
    while (rem >= (M * (a + 1) * (a + 2)) / 2) ++a;
    const int u = rem - M * a * (a + 1) / 2;
    const int C = a + 1;
    const int r = u / C, c = u - r * C;
    const int j = a * M + r;
    const int q0 = j * 64;

    const bool causal = (mflag[0] != 0);
    const int T = causal ? (j + 1) : 32;
    const int qq = (T + C - 1) / C;
    const int t0 = c * qq;
    const int t1 = min(t0 + qq, T);
    const int tb = b * 32;
    const unsigned char* padb = pad + (size_t)b * NN;

    const short* qrow = Qb + ((size_t)b * NN + q0 + w*16 + lc) * HD;
    const short8 qf0 = *(const short8*)(qrow + quad * 8);
    const short8 qf1 = *(const short8*)(qrow + 32 + quad * 8);

    f32x4 o[4];
#pragma unroll
    for (int t = 0; t < 4; ++t)
#pragma unroll
        for (int rr = 0; rr < 4; ++rr) o[t][rr] = 0.f;
    float lacc = 0.f;

    {
        const short* gk = Kb + ((size_t)(tb + t0) << 12) + w*1024 + lane*8;
        const short* gv = Vt + ((size_t)(tb + t0) << 12) + w*1024 + lane*8;
        short* lk = &sK[0][w*1024 + lane*8];
        short* lv = &sV[0][w*1024 + lane*8];
        gl16(gk, lk); gl16(gk + 512, lk + 512);
        gl16(gv, lv); gl16(gv + 512, lv + 512);
    }

    int buf = 0;
    const int sw = lc & 7;
    for (int kt = t0; kt < t1; ++kt, buf ^= 1){
        __syncthreads();
        if (kt + 1 < t1){
            const short* gk = Kb + ((size_t)(tb + kt + 1) << 12) + w*1024 + lane*8;
            const short* gv = Vt + ((size_t)(tb + kt + 1) << 12) + w*1024 + lane*8;
            short* lk = &sK[buf ^ 1][w*1024 + lane*8];
            short* lv = &sV[buf ^ 1][w*1024 + lane*8];
            gl16(gk, lk); gl16(gk + 512, lk + 512);
            gl16(gv, lv); gl16(gv + 512, lv + 512);
        }
        const int k0 = kt * 64;
        short8 kf0[4], kf1[4], vf0[4], vf1[4];
#pragma unroll
        for (int t = 0; t < 4; ++t){
            const int row = (t*16 + lc) * 64;
            kf0[t] = *(const short8*)&sK[buf][row + ((quad ^ sw) << 3)];
            kf1[t] = *(const short8*)&sK[buf][row + (((quad + 4) ^ sw) << 3)];
            vf0[t] = *(const short8*)&sV[buf][row + ((quad ^ sw) << 3)];
            vf1[t] = *(const short8*)&sV[buf][row + (((quad + 4) ^ sw) << 3)];
        }
        f32x4 st[4];
#pragma unroll
        for (int t = 0; t < 4; ++t){
#pragma unroll
            for (int rr = 0; rr < 4; ++rr) st[t][rr] = 0.f;
            st[t] = __builtin_amdgcn_mfma_f32_16x16x32_bf16(kf0[t], qf0, st[t], 0,0,0);
            st[t] = __builtin_amdgcn_mfma_f32_16x16x32_bf16(kf1[t], qf1, st[t], 0,0,0);
        }
        const bool dg = causal && (kt == j);
        const int thr = q0 + w*16 + lc - k0;
#pragma unroll
        for (int t = 0; t < 4; ++t){
            uchar4 pb = *(const uchar4*)(padb + k0 + t*16 + quad*4);
            float e[4];
#pragma unroll
            for (int rr = 0; rr < 4; ++rr){
                float v = st[t][rr];
                const unsigned char pr = (rr==0)?pb.x:(rr==1)?pb.y:(rr==2)?pb.z:pb.w;
                const int nloc = t*16 + quad*4 + rr;
                if (pr || (dg && nloc > thr)) v = -INFINITY;
                e[rr] = exp2f(v);
                lacc += e[rr];
            }
            union { short4v s4; unsigned uu[2]; } pk;
            pk.uu[0] = pkbf(e[0], e[1]);
            pk.uu[1] = pkbf(e[2], e[3]);
            *(short4v*)&sP[w][lc][t*16 + quad*4] = pk.s4;
        }
        const short8 pf0 = *(const short8*)&sP[w][lc][quad*8];
        const short8 pf1 = *(const short8*)&sP[w][lc][32 + quad*8];
#pragma unroll
        for (int t = 0; t < 4; ++t){
            o[t] = __builtin_amdgcn_mfma_f32_16x16x32_bf16(pf0, vf0[t], o[t], 0,0,0);
            o[t] = __builtin_amdgcn_mfma_f32_16x16x32_bf16(pf1, vf1[t], o[t], 0,0,0);
        }
    }

    lacc += __shfl_xor(lacc, 16);
    lacc += __shfl_xor(lacc, 32);

    if (C == 1){
        float linv[4];
#pragma unroll
        for (int rr = 0; rr < 4; ++rr) linv[rr] = 1.f / __shfl(lacc, quad*4 + rr);
#pragma unroll
        for (int rr = 0; rr < 4; ++rr){
            float* orow = out + ((size_t)b*NN + q0 + w*16 + quad*4 + rr)*HD;
#pragma unroll
            for (int t = 0; t < 4; ++t) orow[t*16 + lc] = o[t][rr] * linv[rr];
        }
    } else {
        const int pu = b*PPB + (M*a*(a+1)/2 - M) + r*C + c;
        short* op = Op + (size_t)pu * 4096;
#pragma unroll
        for (int t = 0; t < 4; ++t)
#pragma unroll
            for (int rr = 0; rr < 4; ++rr)
                op[(w*16 + quad*4 + rr)*64 + t*16 + lc] = f2bf(o[t][rr]);
        if (lane < 16) Lp[pu*64 + w*16 + lane] = lacc;
    }
}

// ---------------- Combine: one thread per output element.
template<int SH>
__global__ __launch_bounds__(256)
void attn_combine(const float* __restrict__ Lp, const short* __restrict__ Op,
                  float* __restrict__ out)
{
    constexpr int M    = 1 << SH;
    constexpr int UPB  = M * (32/M) * (32/M + 1) / 2;
    constexpr int PPB  = UPB - M;
    constexpr int NSTR = 32 - M;
    const int tid = threadIdx.x, lane = tid & 63;
    const int unit = blockIdx.x;
    const int per_b = NSTR * 16;
    const int b = unit / per_b;
    const int rem = unit - b * per_b;
    const int j = M + (rem >> 4);
    const int row = (rem & 15) * 4 + (tid >> 6);
    const int a = j >> SH;
    const int C = a + 1;
    const int r = j - a * M;
    const int pu0 = b*PPB + (M*a*(a+1)/2 - M) + r*C;

    float l = 0.f, acc = 0.f;
    for (int cc = 0; cc < C; ++cc){
        l   += Lp[(pu0 + cc)*64 + row];
        acc += bf2f(Op[(size_t)(pu0 + cc)*4096 + row*64 + lane]);
    }
    out[((size_t)b*NN + j*64 + row)*HD + lane] = acc / l;
}

extern "C" void kernel_launch(void* const* d_in, const int* in_sizes, int n_in,
                              void* d_out, int out_size, void* d_ws, size_t ws_size,
                              hipStream_t stream) {
    const float* key_in   = (const float*)d_in[0];
    const float* query_in = (const float*)d_in[1];
    const float* value_in = (const float*)d_in[2];
    const unsigned char* pad = (const unsigned char*)d_in[3];
    const int* mflag      = (const int*)d_in[4];
    const float* Wk       = (const float*)d_in[5];
    // W_query / W_value unused — reference applies W_key to Q, K and V.

    short* Qb = (short*)d_ws;                    // 2 MiB (pre-scaled by QSCALE)
    short* Kb = Qb + (size_t)MROWS*HD;           // 2 MiB, swizzled tiles
    short* Vt = Kb + (size_t)MROWS*HD;           // 2 MiB, swizzled tiles [d][n]
    short* Wtf = Vt + (size_t)MROWS*HD;          // 64 KiB, frag order
    float* Lp = (float*)(Wtf + D_EMB*HD);

    wt_kernel<<<64, 256, 0, stream>>>(Wk, Wtf);
    proj_kernel<<<1536, 256, 0, stream>>>(query_in, key_in, value_in, Wtf, Qb, Kb, Vt);

    if (ws_size >= (size_t)15818752){
        // SH=2: 1152 part-blocks, <=4 tiles each; Lp 1120*64 f32, Op 1120*4096 bf16
        short* Op = (short*)(Lp + 1120*64);
        attn_part<2><<<1152, 256, 0, stream>>>(Qb, Kb, Vt, pad, mflag, (float*)d_out, Lp, Op);
        attn_combine<2><<<BB*28*16, 256, 0, stream>>>(Lp, Op, (float*)d_out);
    } else {
        // SH=3: 640 part-blocks, <=8 tiles each; 11.2 MB total (proven fit)
        short* Op = (short*)(Lp + 576*64);
        attn_part<3><<<640, 256, 0, stream>>>(Qb, Kb, Vt, pad, mflag, (float*)d_out, Lp, Op);
        attn_combine<3><<<BB*24*16, 256, 0, stream>>>(Lp, Op, (float*)d_out);
    }
}

// Round 3
// 163.601 us; speedup vs baseline: 1.0504x; 1.0268x over previous
//
#include <hip/hip_runtime.h>
#include <hip/hip_bf16.h>
#include <math.h>

#define D_EMB 512
#define HD 64
#define BB 8
#define NN 2048
#define MROWS (BB*NN)   // 16384

typedef short short8  __attribute__((ext_vector_type(8)));
typedef short short4v __attribute__((ext_vector_type(4)));
typedef float f32x4   __attribute__((ext_vector_type(4)));

// scale(1/sqrt(512)) * log2(e): folded into Qb so P = exp2(S') directly
#define QSCALE 0.063758708f

__device__ __forceinline__ short f2bf(float x){
    unsigned u = __float_as_uint(x);
    unsigned r = (u + 0x7fffu + ((u >> 16) & 1u)) >> 16;
    return (short)r;
}
__device__ __forceinline__ float bf2f(short b){
    return __uint_as_float(((unsigned)(unsigned short)b) << 16);
}
__device__ __forceinline__ unsigned pkbf(float a, float b){
    __hip_bfloat162 h = __float22bfloat162_rn(make_float2(a, b));
    unsigned u; __builtin_memcpy(&u, &h, 4); return u;
}
// async global->LDS, 16B per lane (global_load_lds_dwordx4)
__device__ __forceinline__ void gl16(const void* g, void* l){
    __builtin_amdgcn_global_load_lds(
        (const __attribute__((address_space(1))) unsigned*)g,
        (__attribute__((address_space(3))) unsigned*)l, 16, 0, 0);
}

// ---------------- Wtf: W[k][n] f32 -> bf16 in MFMA B-frag order
// off = ((c16*4 + t)*64 + lane)*8 + j  with c16=k>>5, t=n>>4,
// lane=((k>>3)&3)*16 + (n&15), j=k&7
__global__ __launch_bounds__(256)
void wt_kernel(const float* __restrict__ W, short* __restrict__ Wtf){
    for (int idx = blockIdx.x * 256 + threadIdx.x; idx < D_EMB*HD; idx += 64*256){
        int k = idx >> 6, n = idx & 63;
        int off = (((k >> 5)*4 + (n >> 4))*64 + ((k >> 3) & 3)*16 + (n & 15))*8 + (k & 7);
        Wtf[off] = f2bf(W[idx]);
    }
}

// ---------------- Projection, R11: gl16-staged double-buffered pipeline.
// Post-mortem R8-R10: three register-prefetch structures all pinned at
// ~41 us / 1.37 TB/s -> measured in-flight ~3.4 KB/CU. The compiler
// re-sinks VGPR prefetch to use sites under reg pressure (R8 VGPR=32
// proved it). Fix: prefetch through global_load_lds, which has NO dest
// VGPR -> the 8 issued gl16/wave (32 KB/block) are structurally in
// flight; barrier -> issue-next -> compute -> barrier keeps ~64 KB/CU
// outstanding (2 blocks/CU) >> ~9 KB needed to saturate HBM.
// Wtf B-frags hoisted to 64 VGPRs ONCE (same for all groups) so the
// vmcnt queue holds only staging; also cuts Wtf reads 192 MB -> 2 MB.
// X tile in LDS is pair(32B)-XOR-swizzled (involution applied on gl16
// SOURCE and ds_read side): row=lc frag reads would be 16-way bank
// conflicts on a linear [16][512] tile; swizzled they are bank-uniform.
__global__ __launch_bounds__(256, 2)
void proj_kernel(const float* __restrict__ Xq, const float* __restrict__ Xk,
                 const float* __restrict__ Xv, const short* __restrict__ Wtf,
                 short* __restrict__ Qb, short* __restrict__ Kb,
                 short* __restrict__ Vt)
{
    __shared__ float sX[2][16][512];          // 2 x 32 KiB double buffer
    const int tid = threadIdx.x;
    const int lane = tid & 63;
    const int lc = lane & 15, quad = lane >> 4;
    const int w = tid >> 6;                   // wave = output col quarter t

    // B-frags for t=w, all 16 K-slices: 16 x short8 = 64 VGPRs, loaded once.
    short8 bfW[16];
#pragma unroll
    for (int c = 0; c < 16; ++c)
        bfW[c] = *(const short8*)(Wtf + (size_t)(((c*4 + w)*64 + lane)*8));

    // Staging decode: LDS linear slot -> pre-swizzled global source.
    // LDS byte L = pass*4096 + tid*16; row = L>>11, pair slot pj = (L>>5)&63,
    // half = (L>>4)&1; source pair j = (pj&~7)|((pj^row)&7)  (involution).
    const int s_pj   = (tid & 127) >> 1;
    const int s_half = tid & 1;

    const int g0 = blockIdx.x * 6;            // 512 blocks x 6 groups = 3072

    {   // prologue stage of group 0 into buffer 0
        const int grp = g0;
        const int tensor = grp >> 10;
        const int rloc = (grp << 4) & (MROWS - 1);
        const float* X = (tensor == 0) ? Xq : (tensor == 1 ? Xk : Xv);
#pragma unroll
        for (int pass = 0; pass < 8; ++pass){
            const int row = pass*2 + (tid >> 7);
            const int j = (s_pj & ~7) | ((s_pj ^ row) & 7);
            gl16(X + (size_t)(rloc + row)*D_EMB + j*8 + s_half*4,
                 &sX[0][0][0] + pass*1024 + tid*4);
        }
    }

    for (int g = 0; g < 6; ++g){
        const int grp = g0 + g;
        const int cur = g & 1;
        __syncthreads();                      // buf[cur] staged (drains vmcnt)
        if (g + 1 < 6){                       // issue next stage NOW; it flies
            const int ng = grp + 1;           // under compute + next barrier
            const int tensor = ng >> 10;
            const int rloc = (ng << 4) & (MROWS - 1);
            const float* X = (tensor == 0) ? Xq : (tensor == 1 ? Xk : Xv);
#pragma unroll
            for (int pass = 0; pass < 8; ++pass){
                const int row = pass*2 + (tid >> 7);
                const int j = (s_pj & ~7) | ((s_pj ^ row) & 7);
                gl16(X + (size_t)(rloc + row)*D_EMB + j*8 + s_half*4,
                     &sX[cur ^ 1][0][0] + pass*1024 + tid*4);
            }
        }

        f32x4 acc;
#pragma unroll
        for (int r = 0; r < 4; ++r) acc[r] = 0.f;

#pragma unroll
        for (int c16 = 0; c16 < 16; ++c16){
            const int j = c16*4 + quad;
            const int pj = (j & ~7) | ((j ^ lc) & 7);   // same involution
            const float* p = &sX[cur][lc][0] + pj*8;
            float4 f0 = *(const float4*)p;
            float4 f1 = *(const float4*)(p + 4);
            union { short8 s8; unsigned u[4]; } a;
            a.u[0] = pkbf(f0.x, f0.y); a.u[1] = pkbf(f0.z, f0.w);
            a.u[2] = pkbf(f1.x, f1.y); a.u[3] = pkbf(f1.z, f1.w);
            acc = __builtin_amdgcn_mfma_f32_16x16x32_bf16(a.s8, bfW[c16], acc, 0,0,0);
        }

        // Epilogue for this group (stores drain at the next barrier).
        const int tensor = grp >> 10;
        const int rloc = (grp << 4) & (MROWS - 1);
        if (tensor == 0){
#pragma unroll
            for (int r = 0; r < 4; ++r)
                Qb[(size_t)(rloc + quad*4 + r)*HD + w*16 + lc] = f2bf(acc[r] * QSCALE);
        } else if (tensor == 1){
            // K tile: tile=R>>6; off = nin*64 + ((d>>3)^(nin&7))*8 + (d&7)
#pragma unroll
            for (int r = 0; r < 4; ++r){
                const int R = rloc + quad*4 + r;
                const int nin = R & 63;
                const int off = ((R >> 6) << 12) + nin*64
                              + ((((w << 1) | (lc >> 3)) ^ (nin & 7)) << 3) + (lc & 7);
                Kb[off] = f2bf(acc[r]);
            }
        } else {
            // V tile: tile=R>>6; off = d*64 + ((nin>>3)^(d&7))*8 + (nin&7)
#pragma unroll
            for (int r = 0; r < 4; ++r){
                const int R = rloc + quad*4 + r;
                const int nin = R & 63;
                const int d = w*16 + lc;
                const int off = ((R >> 6) << 12) + d*64
                              + (((nin >> 3) ^ (lc & 7)) << 3) + (nin & 7);
                Vt[off] = f2bf(acc[r]);
            }
        }
    }
}

// ---------------- Attention: block = (b, 64-row q-block j, k-chunk c).
// 4 waves share double-buffered global_load_lds-staged K/V tiles. (unchanged)
template<int SH>
__global__ __launch_bounds__(256)
void attn_part(const short* __restrict__ Qb, const short* __restrict__ Kb,
               const short* __restrict__ Vt, const unsigned char* __restrict__ pad,
               const int* __restrict__ mflag, float* __restrict__ out,
               float* __restrict__ Lp, short* __restrict__ Op)
{
    constexpr int M   = 1 << SH;
    constexpr int NG  = 32 / M;
    constexpr int UPB = M * NG * (NG + 1) / 2;
    constexpr int PPB = UPB - M;

    __shared__ short sK[2][4096];
    __shared__ short sV[2][4096];
    __shared__ short sP[4][16][80];

    const int tid = threadIdx.x, lane = tid & 63, lc = lane & 15, quad = lane >> 4, w = tid >> 6;
    const int unit = blockIdx.x;
    const int b = unit / UPB;
    const int rem = unit - b * UPB;
    int a = 0;
    while (rem >= (M * (a + 1) * (a + 2)) / 2) ++a;
    const int u = rem - M * a * (a + 1) / 2;
    const int C = a + 1;
    const int r = u / C, c = u - r * C;
    const int j = a * M + r;
    const int q0 = j * 64;

    const bool causal = (mflag[0] != 0);
    const int T = causal ? (j + 1) : 32;
    const int qq = (T + C - 1) / C;
    const int t0 = c * qq;
    const int t1 = min(t0 + qq, T);
    const int tb = b * 32;
    const unsigned char* padb = pad + (size_t)b * NN;

    const short* qrow = Qb + ((size_t)b * NN + q0 + w*16 + lc) * HD;
    const short8 qf0 = *(const short8*)(qrow + quad * 8);
    const short8 qf1 = *(const short8*)(qrow + 32 + quad * 8);

    f32x4 o[4];
#pragma unroll
    for (int t = 0; t < 4; ++t)
#pragma unroll
        for (int rr = 0; rr < 4; ++rr) o[t][rr] = 0.f;
    float lacc = 0.f;

    {
        const short* gk = Kb + ((size_t)(tb + t0) << 12) + w*1024 + lane*8;
        const short* gv = Vt + ((size_t)(tb + t0) << 12) + w*1024 + lane*8;
        short* lk = &sK[0][w*1024 + lane*8];
        short* lv = &sV[0][w*1024 + lane*8];
        gl16(gk, lk); gl16(gk + 512, lk + 512);
        gl16(gv, lv); gl16(gv + 512, lv + 512);
    }

    int buf = 0;
    const int sw = lc & 7;
    for (int kt = t0; kt < t1; ++kt, buf ^= 1){
        __syncthreads();
        if (kt + 1 < t1){
            const short* gk = Kb + ((size_t)(tb + kt + 1) << 12) + w*1024 + lane*8;
            const short* gv = Vt + ((size_t)(tb + kt + 1) << 12) + w*1024 + lane*8;
            short* lk = &sK[buf ^ 1][w*1024 + lane*8];
            short* lv = &sV[buf ^ 1][w*1024 + lane*8];
            gl16(gk, lk); gl16(gk + 512, lk + 512);
            gl16(gv, lv); gl16(gv + 512, lv + 512);
        }
        const int k0 = kt * 64;
        short8 kf0[4], kf1[4], vf0[4], vf1[4];
#pragma unroll
        for (int t = 0; t < 4; ++t){
            const int row = (t*16 + lc) * 64;
            kf0[t] = *(const short8*)&sK[buf][row + ((quad ^ sw) << 3)];
            kf1[t] = *(const short8*)&sK[buf][row + (((quad + 4) ^ sw) << 3)];
            vf0[t] = *(const short8*)&sV[buf][row + ((quad ^ sw) << 3)];
            vf1[t] = *(const short8*)&sV[buf][row + (((quad + 4) ^ sw) << 3)];
        }
        f32x4 st[4];
#pragma unroll
        for (int t = 0; t < 4; ++t){
#pragma unroll
            for (int rr = 0; rr < 4; ++rr) st[t][rr] = 0.f;
            st[t] = __builtin_amdgcn_mfma_f32_16x16x32_bf16(kf0[t], qf0, st[t], 0,0,0);
            st[t] = __builtin_amdgcn_mfma_f32_16x16x32_bf16(kf1[t], qf1, st[t], 0,0,0);
        }
        const bool dg = causal && (kt == j);
        const int thr = q0 + w*16 + lc - k0;
#pragma unroll
        for (int t = 0; t < 4; ++t){
            uchar4 pb = *(const uchar4*)(padb + k0 + t*16 + quad*4);
            float e[4];
#pragma unroll
            for (int rr = 0; rr < 4; ++rr){
                float v = st[t][rr];
                const unsigned char pr = (rr==0)?pb.x:(rr==1)?pb.y:(rr==2)?pb.z:pb.w;
                const int nloc = t*16 + quad*4 + rr;
                if (pr || (dg && nloc > thr)) v = -INFINITY;
                e[rr] = exp2f(v);
                lacc += e[rr];
            }
            union { short4v s4; unsigned uu[2]; } pk;
            pk.uu[0] = pkbf(e[0], e[1]);
            pk.uu[1] = pkbf(e[2], e[3]);
            *(short4v*)&sP[w][lc][t*16 + quad*4] = pk.s4;
        }
        const short8 pf0 = *(const short8*)&sP[w][lc][quad*8];
        const short8 pf1 = *(const short8*)&sP[w][lc][32 + quad*8];
#pragma unroll
        for (int t = 0; t < 4; ++t){
            o[t] = __builtin_amdgcn_mfma_f32_16x16x32_bf16(pf0, vf0[t], o[t], 0,0,0);
            o[t] = __builtin_amdgcn_mfma_f32_16x16x32_bf16(pf1, vf1[t], o[t], 0,0,0);
        }
    }

    lacc += __shfl_xor(lacc, 16);
    lacc += __shfl_xor(lacc, 32);

    if (C == 1){
        float linv[4];
#pragma unroll
        for (int rr = 0; rr < 4; ++rr) linv[rr] = 1.f / __shfl(lacc, quad*4 + rr);
#pragma unroll
        for (int rr = 0; rr < 4; ++rr){
            float* orow = out + ((size_t)b*NN + q0 + w*16 + quad*4 + rr)*HD;
#pragma unroll
            for (int t = 0; t < 4; ++t) orow[t*16 + lc] = o[t][rr] * linv[rr];
        }
    } else {
        const int pu = b*PPB + (M*a*(a+1)/2 - M) + r*C + c;
        short* op = Op + (size_t)pu * 4096;
#pragma unroll
        for (int t = 0; t < 4; ++t)
#pragma unroll
            for (int rr = 0; rr < 4; ++rr)
                op[(w*16 + quad*4 + rr)*64 + t*16 + lc] = f2bf(o[t][rr]);
        if (lane < 16) Lp[pu*64 + w*16 + lane] = lacc;
    }
}

// ---------------- Combine: one thread per output element.
template<int SH>
__global__ __launch_bounds__(256)
void attn_combine(const float* __restrict__ Lp, const short* __restrict__ Op,
                  float* __restrict__ out)
{
    constexpr int M    = 1 << SH;
    constexpr int UPB  = M * (32/M) * (32/M + 1) / 2;
    constexpr int PPB  = UPB - M;
    constexpr int NSTR = 32 - M;
    const int tid = threadIdx.x, lane = tid & 63;
    const int unit = blockIdx.x;
    const int per_b = NSTR * 16;
    const int b = unit / per_b;
    const int rem = unit - b * per_b;
    const int j = M + (rem >> 4);
    const int row = (rem & 15) * 4 + (tid >> 6);
    const int a = j >> SH;
    const int C = a + 1;
    const int r = j - a * M;
    const int pu0 = b*PPB + (M*a*(a+1)/2 - M) + r*C;

    float l = 0.f, acc = 0.f;
    for (int cc = 0; cc < C; ++cc){
        l   += Lp[(pu0 + cc)*64 + row];
        acc += bf2f(Op[(size_t)(pu0 + cc)*4096 + row*64 + lane]);
    }
    out[((size_t)b*NN + j*64 + row)*HD + lane] = acc / l;
}

extern "C" void kernel_launch(void* const* d_in, const int* in_sizes, int n_in,
                              void* d_out, int out_size, void* d_ws, size_t ws_size,
                              hipStream_t stream) {
    const float* key_in   = (const float*)d_in[0];
    const float* query_in = (const float*)d_in[1];
    const float* value_in = (const float*)d_in[2];
    const unsigned char* pad = (const unsigned char*)d_in[3];
    const int* mflag      = (const int*)d_in[4];
    const float* Wk       = (const float*)d_in[5];
    // W_query / W_value unused — reference applies W_key to Q, K and V.

    short* Qb = (short*)d_ws;                    // 2 MiB (pre-scaled by QSCALE)
    short* Kb = Qb + (size_t)MROWS*HD;           // 2 MiB, swizzled tiles
    short* Vt = Kb + (size_t)MROWS*HD;           // 2 MiB, swizzled tiles [d][n]
    short* Wtf = Vt + (size_t)MROWS*HD;          // 64 KiB, frag order
    float* Lp = (float*)(Wtf + D_EMB*HD);

    wt_kernel<<<64, 256, 0, stream>>>(Wk, Wtf);
    proj_kernel<<<512, 256, 0, stream>>>(query_in, key_in, value_in, Wtf, Qb, Kb, Vt);

    if (ws_size >= (size_t)15818752){
        // SH=2: 1152 part-blocks, <=4 tiles each; Lp 1120*64 f32, Op 1120*4096 bf16
        short* Op = (short*)(Lp + 1120*64);
        attn_part<2><<<1152, 256, 0, stream>>>(Qb, Kb, Vt, pad, mflag, (float*)d_out, Lp, Op);
        attn_combine<2><<<BB*28*16, 256, 0, stream>>>(Lp, Op, (float*)d_out);
    } else {
        // SH=3: 640 part-blocks, <=8 tiles each; 11.2 MB total (proven fit)
        short* Op = (short*)(Lp + 576*64);
        attn_part<3><<<640, 256, 0, stream>>>(Qb, Kb, Vt, pad, mflag, (float*)d_out, Lp, Op);
        attn_combine<3><<<BB*24*16, 256, 0, stream>>>(Lp, Op, (float*)d_out);
    }
}